// Round 10
// baseline (30.890 us; speedup 1.0000x reference)
//
#include <hip/hip_runtime.h>

#define SCALE_F 173.71779276130078f   // 400 / ln(10)
#define BLOCK 256
#define TPT 2                          // consecutive tokens per thread
#define TOK_PER_BLOCK (BLOCK * TPT)    // 512 tokens, 12KB staged

typedef float v2f __attribute__((ext_vector_type(2)));

__global__ void zero_ws_kernel(float* __restrict__ ws, int n) {
    int i = blockIdx.x * 256 + threadIdx.x;
    if (i < n) ws[i] = 0.0f;
}

__device__ __forceinline__ int swz(int q) { return q ^ ((q >> 3) & 7); }

__global__ __launch_bounds__(BLOCK, 8) void strength_main_kernel(
    const float* __restrict__ x,    // [N][6]
    const float* __restrict__ W1,   // [6][32]
    const float* __restrict__ b1,   // [32]
    const float* __restrict__ wr,   // [32]
    const float* __restrict__ brp,  // scalar
    const float* __restrict__ wz,   // [32]
    const float* __restrict__ bzp,  // scalar
    const int*   __restrict__ seg,  // [N] sorted
    int N,
    float* __restrict__ num,        // [G]
    float* __restrict__ den)        // [G]
{
    __shared__ float4 xs[TOK_PER_BLOCK * 6 / 4];   // 768 float4 = 12KB

    const int tid    = threadIdx.x;
    const int lane   = tid & 63;
    const int bstart = blockIdx.x * TOK_PER_BLOCK;
    const int t0     = bstart + tid * TPT;

    float a[TPT * 6];
    int   sg[TPT];
    int   kmax;

    if (bstart + TOK_PER_BLOCK <= N) {
        kmax = TPT;
        // ---- coalesced stage: 3 float4/thread, lane-consecutive (1KB/instr) ----
        const float4* xg = (const float4*)(x + (size_t)bstart * 6);
        #pragma unroll
        for (int i = 0; i < 3; ++i) {
            int q = tid + BLOCK * i;
            xs[swz(q)] = xg[q];
        }
        __syncthreads();
        // ---- conflict-free swizzled reads of my 2 tokens (48B) ----
        float4 v0 = xs[swz(3 * tid + 0)];
        float4 v1 = xs[swz(3 * tid + 1)];
        float4 v2 = xs[swz(3 * tid + 2)];
        a[0] = v0.x; a[1]  = v0.y; a[2]  = v0.z; a[3]  = v0.w;
        a[4] = v1.x; a[5]  = v1.y; a[6]  = v1.z; a[7]  = v1.w;
        a[8] = v2.x; a[9]  = v2.y; a[10] = v2.z; a[11] = v2.w;
        int2 s2 = *(const int2*)(seg + t0);
        sg[0] = s2.x; sg[1] = s2.y;
    } else {
        kmax = (t0 >= N) ? 0 : ((N - t0 < TPT) ? (N - t0) : TPT);
        #pragma unroll
        for (int k = 0; k < TPT; ++k) {
            if (k < kmax) {
                const float* xp = x + (size_t)(t0 + k) * 6;
                #pragma unroll
                for (int i = 0; i < 6; ++i) a[k * 6 + i] = xp[i];
                sg[k] = seg[t0 + k];
            } else {
                #pragma unroll
                for (int i = 0; i < 6; ++i) a[k * 6 + i] = 0.0f;
                sg[k] = -1;
            }
        }
    }

    // ---- token-pair packed math (v_pk_fma_f32), R9 structure ----
    v2f X[6];
    #pragma unroll
    for (int f = 0; f < 6; ++f) X[f] = (v2f){ a[f], a[6 + f] };

    const float brv = *brp;   // uniform -> s_load
    const float bzv = *bzp;

    v2f R = (v2f){brv, brv};
    v2f Z = (v2f){bzv, bzv};

    #pragma unroll 2
    for (int c = 0; c < 16; ++c) {
        const float2 w0 = *(const float2*)&W1[0 * 32 + 2 * c];
        const float2 w1 = *(const float2*)&W1[1 * 32 + 2 * c];
        const float2 w2 = *(const float2*)&W1[2 * 32 + 2 * c];
        const float2 w3 = *(const float2*)&W1[3 * 32 + 2 * c];
        const float2 w4 = *(const float2*)&W1[4 * 32 + 2 * c];
        const float2 w5 = *(const float2*)&W1[5 * 32 + 2 * c];
        const float2 bb = *(const float2*)&b1[2 * c];
        const float2 rr = *(const float2*)&wr[2 * c];
        const float2 zz = *(const float2*)&wz[2 * c];

        #pragma unroll
        for (int j = 0; j < 2; ++j) {   // two columns of this pair
            const float wj0 = j ? w0.y : w0.x;
            const float wj1 = j ? w1.y : w1.x;
            const float wj2 = j ? w2.y : w2.x;
            const float wj3 = j ? w3.y : w3.x;
            const float wj4 = j ? w4.y : w4.x;
            const float wj5 = j ? w5.y : w5.x;
            const float bbj = j ? bb.y : bb.x;
            const float rrj = j ? rr.y : rr.x;
            const float zzj = j ? zz.y : zz.x;
            const v2f vw0 = (v2f){wj0, wj0}, vw1 = (v2f){wj1, wj1};
            const v2f vw2 = (v2f){wj2, wj2}, vw3 = (v2f){wj3, wj3};
            const v2f vw4 = (v2f){wj4, wj4}, vw5 = (v2f){wj5, wj5};
            const v2f vbb = (v2f){bbj, bbj};
            const v2f vrr = (v2f){rrj, rrj}, vzz = (v2f){zzj, zzj};
            v2f h = X[0]*vw0 + (X[1]*vw1 + (X[2]*vw2 +
                    (X[3]*vw3 + (X[4]*vw4 + (X[5]*vw5 + vbb)))));
            h = __builtin_elementwise_max(h, (v2f){0.f, 0.f});   // v_pk_max_f32
            R = h * vrr + R;
            Z = h * vzz + Z;
        }
    }

    float rv[TPT] = { R.x, R.y };
    float zv[TPT] = { Z.x, Z.y };

    // ---- per-thread run accumulation; interior boundary flushes to global ----
    int   key = (kmax > 0) ? sg[0] : -1;
    float E = 0.0f, ER = 0.0f;
    #pragma unroll
    for (int k = 0; k < TPT; ++k) {
        if (k < kmax) {
            float e = __expf(zv[k]);       // no max-shift: ratio invariant
            if (sg[k] != key) {
                atomicAdd(&den[key], E);
                atomicAdd(&num[key], ER);
                key = sg[k]; E = 0.0f; ER = 0.0f;
            }
            E += e; ER = fmaf(e, rv[k], ER);
        }
    }

    // ---- one segmented inclusive scan per wave over lane tails ----
    #pragma unroll
    for (int d = 1; d < 64; d <<= 1) {
        int   k2 = __shfl_up(key, d);
        float E2 = __shfl_up(E,   d);
        float R2 = __shfl_up(ER,  d);
        if (lane >= d && k2 == key) { E += E2; ER += R2; }
    }
    int knext = __shfl_down(key, 1);
    bool last = (lane == 63) || (knext != key);
    if (last && key >= 0) {
        atomicAdd(&den[key], E);
        atomicAdd(&num[key], ER);
    }
}

__global__ void finalize_kernel(const float* __restrict__ num,
                                const float* __restrict__ den,
                                float* __restrict__ out, int G) {
    int g = blockIdx.x * 256 + threadIdx.x;
    if (g < G) {
        float d = den[g];
        out[g] = (d > 0.0f) ? (SCALE_F * num[g] / d) : 0.0f;
    }
}

extern "C" void kernel_launch(void* const* d_in, const int* in_sizes, int n_in,
                              void* d_out, int out_size, void* d_ws, size_t ws_size,
                              hipStream_t stream) {
    const float* x   = (const float*)d_in[0];
    const float* W1  = (const float*)d_in[1];
    const float* b1  = (const float*)d_in[2];
    const float* wr  = (const float*)d_in[3];
    const float* br  = (const float*)d_in[4];
    const float* wz  = (const float*)d_in[5];
    const float* bz  = (const float*)d_in[6];
    const int*   seg = (const int*)d_in[7];

    int N = in_sizes[7];     // 2097152
    int G = out_size;        // 8192

    float* num = (float*)d_ws;
    float* den = num + G;
    float* out = (float*)d_out;

    int zn = 2 * G;
    zero_ws_kernel<<<(zn + 255) / 256, 256, 0, stream>>>(num, zn);

    int nblocks = (int)(((long)N + TOK_PER_BLOCK - 1) / TOK_PER_BLOCK);
    strength_main_kernel<<<nblocks, BLOCK, 0, stream>>>(
        x, W1, b1, wr, br, wz, bz, seg, N, num, den);

    finalize_kernel<<<(G + 255) / 256, 256, 0, stream>>>(num, den, out, G);
}